// Round 1
// baseline (567.176 us; speedup 1.0000x reference)
//
#include <hip/hip_runtime.h>

typedef __bf16 bf16;
typedef __bf16 bf16x8 __attribute__((ext_vector_type(8)));
typedef float f32x4 __attribute__((ext_vector_type(4)));

#define NB 64
#define NC 128
#define NOC 128
#define HW 80
#define HPAD 82

// workspace layout (bytes)
#define XT_BYTES  110166016L   // 64*82*82*128*2  bf16, zero-padded halo
#define W2_BYTES  18874368L    // 64*9*128*128*2  bf16, [b][kpos][och][ic]
#define AVG_BYTES 819200L      // 64*128*5*5 fp32
#define WS_NEEDED (XT_BYTES + W2_BYTES + AVG_BYTES)

// ---------------- pool: one wave per 16x16 tile -> avg[b][c][i][j] ----------------
__global__ void pool_kernel(const float* __restrict__ x, float* __restrict__ avg) {
    int wave = (blockIdx.x * blockDim.x + threadIdx.x) >> 6;
    int lane = threadIdx.x & 63;
    int j = wave % 5; int t = wave / 5;
    int i = t % 5; t /= 5;
    int c = t & 127; int b = t >> 7;
    const float* src = x + (((long)(b * 128 + c) * 80) + i * 16) * 80 + j * 16;
    int ry = lane >> 2;          // 0..15
    int rx = (lane & 3) * 4;     // 0,4,8,12
    float4 v = *reinterpret_cast<const float4*>(src + ry * 80 + rx);
    float s = v.x + v.y + v.z + v.w;
    #pragma unroll
    for (int off = 32; off > 0; off >>= 1) s += __shfl_down(s, off, 64);
    if (lane == 0) avg[wave] = s * (1.0f / 256.0f);
}

// ------------- transpose: x[b][c][y][x] f32 -> xT[b][Y][X][c] bf16 (padded) -------------
__global__ void transpose_kernel(const float* __restrict__ x, bf16* __restrict__ xT) {
    __shared__ bf16 tile[64 * 68];
    int b = blockIdx.z, icb = blockIdx.y, pxb = blockIdx.x;
    int t = threadIdx.x;
    int pl = t & 63;        // pixel lane
    int ig = t >> 6;        // 0..3
    const float* src = x + ((long)(b * 128 + icb * 64) * 6400) + pxb * 64;
    #pragma unroll
    for (int it = 0; it < 16; ++it) {
        int ic = ig * 16 + it;
        float v = src[(long)ic * 6400 + pl];
        tile[pl * 68 + ic] = (bf16)v;
    }
    __syncthreads();
    // write: 1024 chunks of 4 bf16 (8B), 4 iters
    #pragma unroll
    for (int it = 0; it < 4; ++it) {
        int idx = it * 256 + t;
        int pxl = idx >> 4;          // 0..63
        int icq = idx & 15;          // 0..15 -> 4 ic each
        int px = pxb * 64 + pxl;
        int Y = px / 80 + 1, X = px % 80 + 1;
        uint2 v = *reinterpret_cast<const uint2*>(&tile[pxl * 68 + icq * 4]);
        *reinterpret_cast<uint2*>(&xT[(((long)b * 82 + Y) * 82 + X) * 128 + icb * 64 + icq * 4]) = v;
    }
}

// ------------- attention: avg -> att -> sigmoid -> dyn_w, W2[b][p][och][ic] bf16 -------------
__global__ void att_kernel(const float* __restrict__ avg, const float* __restrict__ weight,
                           const float* __restrict__ w_att, const float* __restrict__ b_att,
                           bf16* __restrict__ W2) {
    __shared__ float sa[25];
    int b = blockIdx.x >> 7, och = blockIdx.x & 127;
    int ic = threadIdx.x;
    if (ic < 25) sa[ic] = avg[(long)blockIdx.x * 25 + ic];
    __syncthreads();
    int o = och * 128 + ic;
    float wa[9];
    #pragma unroll
    for (int j = 0; j < 9; ++j) wa[j] = w_att[(long)o * 9 + j];
    float bias = b_att[o];
    const float* wst = weight + (long)o * 9;
    #pragma unroll
    for (int kh = 0; kh < 3; ++kh) {
        #pragma unroll
        for (int kw = 0; kw < 3; ++kw) {
            float z = bias;
            #pragma unroll
            for (int di = 0; di < 3; ++di)
                #pragma unroll
                for (int dj = 0; dj < 3; ++dj)
                    z += sa[(kh + di) * 5 + (kw + dj)] * wa[di * 3 + dj];
            float s = 1.0f / (1.0f + __expf(-z));
            float dw = wst[kh * 3 + kw] * s;
            int p = kh * 3 + kw;
            W2[(((long)b * 9 + p) * 128 + och) * 128 + ic] = (bf16)dw;
        }
    }
}

// ------------- main conv as implicit GEMM, bf16 MFMA 16x16x32 -------------
// block: 128 och x 128 pix (16w x 8h), 256 thr = 4 waves, wave = 64 och x 64 pix (4x4 subtiles)
__global__ __launch_bounds__(256, 2)
void conv_gemm(const bf16* __restrict__ xT, const bf16* __restrict__ W2,
               float* __restrict__ out) {
    __shared__ bf16 Xs[180 * 128];   // [pf=r*18+cx][ic], 16B-block XOR swizzled by (pf&7)
    __shared__ bf16 Ws[128 * 64];    // [och][icl],       16B-block XOR swizzled by (och&7)
    int b = blockIdx.z;
    int px0 = blockIdx.x * 16;       // 0..64
    int py0 = blockIdx.y * 8;        // 0..72
    int t = threadIdx.x;
    int wave = t >> 6, lane = t & 63;
    int q = lane >> 4;               // quad
    int li = lane & 15;

    // ---- stage X tile: rows py0..py0+9, cols px0..px0+17 (padded coords), all 128 ic
    {
        const bf16* src = xT + (((long)b * 82 + py0) * 82 + px0) * 128;
        #pragma unroll
        for (int it = 0; it < 12; ++it) {
            int idx = it * 256 + t;
            if (idx < 2880) {
                int pf = idx >> 4, icb = idx & 15;
                int r = pf / 18, cx = pf - r * 18;
                uint4 v = *reinterpret_cast<const uint4*>(src + ((long)r * 82 + cx) * 128 + icb * 8);
                *reinterpret_cast<uint4*>(&Xs[pf * 128 + ((icb ^ (pf & 7)) * 8)]) = v;
            }
        }
    }

    f32x4 acc[4][4];
    #pragma unroll
    for (int i = 0; i < 4; ++i)
        #pragma unroll
        for (int j = 0; j < 4; ++j) acc[i][j] = (f32x4){0.f, 0.f, 0.f, 0.f};

    int ow = (wave >> 1) * 64;   // och offset of this wave
    int nw = (wave & 1) * 64;    // pixel offset of this wave

    for (int p = 0; p < 9; ++p) {
        int kh = p / 3, kw = p - kh * 3;
        for (int h = 0; h < 2; ++h) {
            __syncthreads();
            // stage W half: 128 och x 64 ic
            {
                const bf16* wsrc = W2 + ((long)b * 9 + p) * 128 * 128 + h * 64;
                #pragma unroll
                for (int it = 0; it < 4; ++it) {
                    int idx = it * 256 + t;
                    int och = idx >> 3, icb = idx & 7;
                    uint4 v = *reinterpret_cast<const uint4*>(wsrc + och * 128 + icb * 8);
                    *reinterpret_cast<uint4*>(&Ws[och * 64 + ((icb ^ (och & 7)) * 8)]) = v;
                }
            }
            __syncthreads();
            #pragma unroll
            for (int k2 = 0; k2 < 2; ++k2) {
                int ic0 = k2 * 32;
                bf16x8 af[4], bfr[4];
                #pragma unroll
                for (int mi = 0; mi < 4; ++mi) {
                    int och = ow + mi * 16 + li;
                    int icb = (ic0 >> 3) + q;                 // 0..7
                    af[mi] = *reinterpret_cast<const bf16x8*>(&Ws[och * 64 + ((icb ^ (och & 7)) * 8)]);
                }
                #pragma unroll
                for (int ni = 0; ni < 4; ++ni) {
                    int n = nw + ni * 16 + li;
                    int oy = n >> 4, ox = n & 15;
                    int pf = (oy + kh) * 18 + ox + kw;
                    int icbx = h * 8 + (ic0 >> 3) + q;        // 0..15
                    bfr[ni] = *reinterpret_cast<const bf16x8*>(&Xs[pf * 128 + ((icbx ^ (pf & 7)) * 8)]);
                }
                #pragma unroll
                for (int mi = 0; mi < 4; ++mi)
                    #pragma unroll
                    for (int ni = 0; ni < 4; ++ni)
                        acc[mi][ni] = __builtin_amdgcn_mfma_f32_16x16x32_bf16(af[mi], bfr[ni], acc[mi][ni], 0, 0, 0);
            }
        }
    }

    // epilogue: D[row=q*4+reg][col=li]; row->och, col->pixel
    #pragma unroll
    for (int mi = 0; mi < 4; ++mi) {
        #pragma unroll
        for (int ni = 0; ni < 4; ++ni) {
            int n = nw + ni * 16 + li;
            int oy = py0 + (n >> 4), ox = px0 + (n & 15);
            #pragma unroll
            for (int r = 0; r < 4; ++r) {
                int och = ow + mi * 16 + q * 4 + r;
                out[((long)(b * 128 + och) * 80 + oy) * 80 + ox] = acc[mi][ni][r];
            }
        }
    }
}

extern "C" void kernel_launch(void* const* d_in, const int* in_sizes, int n_in,
                              void* d_out, int out_size, void* d_ws, size_t ws_size,
                              hipStream_t stream) {
    const float* x      = (const float*)d_in[0];
    const float* weight = (const float*)d_in[1];
    const float* w_att  = (const float*)d_in[2];
    const float* b_att  = (const float*)d_in[3];
    float* out = (float*)d_out;

    if (ws_size < (size_t)WS_NEEDED) return;  // workspace too small: fail loudly (wrong output)

    char* ws = (char*)d_ws;
    bf16* xT  = (bf16*)ws;
    bf16* W2  = (bf16*)(ws + XT_BYTES);
    float* avg = (float*)(ws + XT_BYTES + W2_BYTES);

    // zero xT (halo must be 0; ws is re-poisoned each call)
    hipMemsetAsync(xT, 0, XT_BYTES, stream);

    pool_kernel<<<51200, 256, 0, stream>>>(x, avg);
    transpose_kernel<<<dim3(100, 2, 64), 256, 0, stream>>>(x, xT);
    att_kernel<<<8192, 128, 0, stream>>>(avg, weight, w_att, b_att, W2);
    conv_gemm<<<dim3(5, 10, 64), 256, 0, stream>>>(xT, W2, out);
}